// Round 12
// baseline (221.129 us; speedup 1.0000x reference)
//
#include <hip/hip_runtime.h>

typedef unsigned short u16;
typedef __attribute__((ext_vector_type(8))) short short8;   // 8 x bf16 (4 VGPRs)
typedef __attribute__((ext_vector_type(4))) short short4v;  // 4 x bf16 (2 VGPRs)
typedef __attribute__((ext_vector_type(4))) float f32x4;    // MFMA accumulator

#if __has_builtin(__builtin_amdgcn_mfma_f32_16x16x16bf16_1k)
#define PV16 1
#else
#define PV16 0
#endif

__device__ __forceinline__ u16 f2bf(float f){
  union { float f; unsigned u; } v; v.f = f;
  unsigned u = v.u;
  u += 0x7fffu + ((u >> 16) & 1u);   // RNE
  return (u16)(u >> 16);
}
__device__ __forceinline__ float bf2f(u16 h){
  union { unsigned u; float f; } v; v.u = ((unsigned)h) << 16;
  return v.f;
}

// ---------------------------------------------------------------------------
// Kernel 0b: x [8][256][1024] fp32 -> XT [8][1024][256] bf16 (cast+transpose).
// grid (16 hw-tiles, 4 c-tiles, 8 b).
// ---------------------------------------------------------------------------
__global__ __launch_bounds__(256) void xcast_kernel(
    const float* __restrict__ x, u16* __restrict__ XT)
{
  __shared__ float tile[64][69];
  const int b = blockIdx.z, c0 = blockIdx.y*64, hw0 = blockIdx.x*64;
  const int t = threadIdx.x;
  {
    int r = t >> 2, cs = (t & 3) * 16;    // r = c-local row
    const float* s = x + (size_t)(b*256 + c0 + r)*1024 + hw0 + cs;
    #pragma unroll
    for (int i=0;i<4;i++)
      *(float4*)&tile[r][cs + i*4] = *(const float4*)(s + i*4);
  }
  __syncthreads();
  {
    int hr = t >> 2, cc = (t & 3) * 16;   // hr = hw-local row
    __align__(16) u16 tmp[16];
    #pragma unroll
    for (int i=0;i<16;i++) tmp[i] = f2bf(tile[cc + i][hr]);
    u16* d = XT + (size_t)(b*1024 + hw0 + hr)*256 + c0 + cc;
    *(uint4*)d     = *(uint4*)&tmp[0];
    *(uint4*)(d+8) = *(uint4*)&tmp[8];
  }
}

// ---------------------------------------------------------------------------
// Kernel 1: MFMA projections with FUSED weight cast (fp32 W staged with
// in-flight f2bf).  D[co][q] = sum_c W[co][c] * XT[q][c] (+bias), bf16
// conv-flat out.  proj 0 (theta) pre-scaled by log2(e) -> attn uses raw
// v_exp_f32.  grid (3 proj, 64 qg); block = 128co x 128q, 4 waves.
// ---------------------------------------------------------------------------
__global__ __launch_bounds__(256, 2) void proj_mfma_kernel(
    const u16* __restrict__ XT,
    const float* __restrict__ tw, const float* __restrict__ pw,
    const float* __restrict__ gw,
    const float* __restrict__ tb, const float* __restrict__ pb,
    const float* __restrict__ gb,
    u16* __restrict__ T, u16* __restrict__ PHI, u16* __restrict__ G)
{
  __shared__ __align__(16) u16 Ws[128][136];
  __shared__ __align__(16) u16 Xs[128][136];
  const int proj = blockIdx.x, qg = blockIdx.y;
  const int b = qg >> 3, hw0 = (qg & 7) * 128;
  const int q0 = qg * 128;                        // == b*1024 + hw0
  const float* Wf   = (proj==0) ? tw : (proj==1) ? pw : gw;
  const float* bias = (proj==0) ? tb : (proj==1) ? pb : gb;
  u16* out          = (proj==0) ? T  : (proj==1) ? PHI : G;
  const float scale = (proj==0) ? 1.4426950408889634f : 1.0f;
  const int t = threadIdx.x;
  const int wave = t >> 6, lane = t & 63;
  const int quad = lane >> 4, n16 = lane & 15;

  f32x4 acc[8][2];
  #pragma unroll
  for (int mt=0;mt<8;mt++)
    #pragma unroll
    for (int nt=0;nt<2;nt++){ f32x4 z = {0.f,0.f,0.f,0.f}; acc[mt][nt] = z; }

  for (int c0 = 0; c0 < 256; c0 += 128){
    __syncthreads();
    {
      int row = t >> 1, cb = (t & 1) * 64;
      const float* s1 = Wf + (size_t)row*256 + c0 + cb;
      #pragma unroll
      for (int i=0;i<16;i++){
        float4 v = *(const float4*)(s1 + i*4);
        u16* d = &Ws[row][cb + i*4];
        d[0]=f2bf(v.x); d[1]=f2bf(v.y); d[2]=f2bf(v.z); d[3]=f2bf(v.w);
      }
      const u16* s2 = XT + (size_t)(q0 + row)*256 + c0 + cb;
      #pragma unroll
      for (int i=0;i<8;i++)
        *(uint4*)&Xs[row][cb + i*8] = *(const uint4*)(s2 + i*8);
    }
    __syncthreads();
    #pragma unroll
    for (int kc=0; kc<4; kc++){
      short8 xf[2];
      #pragma unroll
      for (int nt=0;nt<2;nt++)
        xf[nt] = *(const short8*)&Xs[wave*32 + nt*16 + n16][kc*32 + quad*8];
      #pragma unroll
      for (int mt=0;mt<8;mt++){
        short8 wf = *(const short8*)&Ws[mt*16 + n16][kc*32 + quad*8];
        #pragma unroll
        for (int nt=0;nt<2;nt++)
          acc[mt][nt] = __builtin_amdgcn_mfma_f32_16x16x32_bf16(wf, xf[nt], acc[mt][nt], 0, 0, 0);
      }
    }
  }
  #pragma unroll
  for (int mt=0;mt<8;mt++){
    float4 bv = *(const float4*)&bias[mt*16 + quad*4];
    float bb[4] = {bv.x, bv.y, bv.z, bv.w};
    #pragma unroll
    for (int nt=0;nt<2;nt++)
      #pragma unroll
      for (int r=0;r<4;r++)
        out[(size_t)b*131072 + (size_t)(mt*16 + quad*4 + r)*1024
            + hw0 + wave*32 + nt*16 + n16] = f2bf((acc[mt][nt][r] + bb[r]) * scale);
  }
}

// ---------------------------------------------------------------------------
// Kernel 2: bf16 2D transpose, dst[c][r] = src[r][c].  64x64 tiles.
// ---------------------------------------------------------------------------
__global__ __launch_bounds__(256) void transpose_bf_kernel(
    const u16* __restrict__ src, u16* __restrict__ dst, int R, int C)
{
  __shared__ u16 tile[64][72];
  const int t = threadIdx.x;
  const int c0 = blockIdx.x*64, r0 = blockIdx.y*64;
  {
    int rr = t >> 2, cs = (t & 3) * 16;
    const u16* s = src + (size_t)(r0+rr)*C + c0 + cs;
    uint4 a0 = *(const uint4*)s;
    uint4 a1 = *(const uint4*)(s+8);
    *(uint4*)&tile[rr][cs]   = a0;
    *(uint4*)&tile[rr][cs+8] = a1;
  }
  __syncthreads();
  {
    int cc = t >> 2, rs = (t & 3) * 16;
    __align__(16) u16 tmp[16];
    #pragma unroll
    for (int i=0;i<16;i++) tmp[i] = tile[rs+i][cc];
    u16* d = dst + (size_t)(c0+cc)*R + r0 + rs;
    *(uint4*)d     = *(uint4*)&tmp[0];
    *(uint4*)(d+8) = *(uint4*)&tmp[8];
  }
}

// ---------------------------------------------------------------------------
// Kernel 3: flash attention (no-max softmax), LDS-staged K+V, 64-key tiles,
// key-split S=16, block = 4 waves x 64q.  R10-verified structure with ONE
// change: the P path.  LAYOUT IDENTITY: QK^T's C-layout (q=lane&15,
// key=quad*4+r) IS the A-operand layout of v_mfma_f32_16x16x16_bf16
// (A[m=lane&15][k=quad*4+j]).  So the exp'd P values feed PV directly
// in-register (pa = the packed pk words), eliminating Pall (36.9 KB LDS),
// 24 LDS ops/tile/wave, and the hard lgkm drain.  B-operand = one b64
// read from Vs (min-cycle).  Guarded: if the 16x16x16 builtin is absent,
// falls back to the verified Pall path (= R10 exactly).
// Staging stays global->VGPR->ds_write (global_load_lds = 5-10x HBM traffic,
// R3+R7; register prefetch = spill, R4+R9+R11).
// ---------------------------------------------------------------------------
__global__ __launch_bounds__(256, 2) void attn_kernel(
    const u16* __restrict__ Tq, const u16* __restrict__ Kk,
    const u16* __restrict__ Vt, u16* __restrict__ Opart,
    float* __restrict__ lpart)
{
  __shared__ __align__(16) u16 Ks[64][136];    // 17408 B
  __shared__ __align__(16) u16 Vs[128][72];    // 18432 B
#if !PV16
  __shared__ __align__(16) u16 Pall[4][4608];  // 4 x [64 q][72]
#endif

  const int t = threadIdx.x;
  const int wave = t >> 6, lane = t & 63;
  const int quad = lane >> 4, n16 = lane & 15;
  const int s  = blockIdx.x & 15;
  const int qg = blockIdx.x >> 4;
  const int q0 = qg*256 + wave*64;
#if !PV16
  u16* Pw = Pall[wave];
  const int wmask = n16 & 14;
#endif
  u16*   Os = Opart + (size_t)s * 1048576;
  float* ls = lpart + (size_t)s * 8192;

  short8 qa[4][4];
  #pragma unroll
  for (int mt=0;mt<4;mt++)
    #pragma unroll
    for (int kc=0;kc<4;kc++)
      qa[mt][kc] = *(const short8*)(Tq + (size_t)(q0 + mt*16 + n16)*128 + kc*32 + quad*8);

  f32x4 o[4][8];
  float lp[4];
  #pragma unroll
  for (int mt=0;mt<4;mt++){
    #pragma unroll
    for (int dt=0;dt<8;dt++){ f32x4 z = {0.f,0.f,0.f,0.f}; o[mt][dt] = z; }
    lp[mt] = 0.f;
  }

  const int krow = t >> 2, kcs = (t & 3) * 32;
  const int vrow = t >> 1, vcs = (t & 1) * 32;

  for (int kt = s*8; kt < s*8 + 8; kt++){
    const int key0 = kt * 64;
    __syncthreads();
    #pragma unroll
    for (int i=0;i<4;i++)
      *(uint4*)&Ks[krow][kcs + i*8] =
        *(const uint4*)(Kk + (size_t)(key0 + krow)*128 + kcs + i*8);
    #pragma unroll
    for (int i=0;i<4;i++)
      *(uint4*)&Vs[vrow][vcs + i*8] =
        *(const uint4*)(Vt + (size_t)vrow*8192 + key0 + vcs + i*8);
    __syncthreads();

#if PV16
    // Fused: per 16-key block, S^T = K Q^T -> exp2 -> in-register P ->
    // PV via 16x16x16 MFMA (C-of-QK layout == A-of-PV16 layout).
    #pragma unroll
    for (int ntk=0; ntk<4; ntk++){
      short8 kf[4];
      #pragma unroll
      for (int kc=0;kc<4;kc++)
        kf[kc] = *(const short8*)&Ks[ntk*16 + n16][kc*32 + quad*8];
      short4v pa[4];
      #pragma unroll
      for (int mtq=0;mtq<4;mtq++){
        f32x4 sa = {0.f,0.f,0.f,0.f};
        #pragma unroll
        for (int kc=0;kc<4;kc++)
          sa = __builtin_amdgcn_mfma_f32_16x16x32_bf16(kf[kc], qa[mtq][kc], sa, 0, 0, 0);
        u16 pb[4];
        #pragma unroll
        for (int r=0;r<4;r++){
          float pe = __builtin_amdgcn_exp2f(sa[r]);
          lp[mtq] += pe;
          pb[r] = f2bf(pe);
        }
        union { unsigned u[2]; short4v v; } pu;
        pu.u[0] = ((unsigned)pb[1] << 16) | pb[0];
        pu.u[1] = ((unsigned)pb[3] << 16) | pb[2];
        pa[mtq] = pu.v;
      }
      __builtin_amdgcn_s_setprio(1);
      #pragma unroll
      for (int dt=0; dt<8; dt++){
        short4v vb = *(const short4v*)&Vs[dt*16 + n16][ntk*16 + quad*4];
        #pragma unroll
        for (int mtq=0;mtq<4;mtq++)
          o[mtq][dt] = __builtin_amdgcn_mfma_f32_16x16x16bf16_1k(pa[mtq], vb, o[mtq][dt], 0, 0, 0);
      }
      __builtin_amdgcn_s_setprio(0);
    }
#else
    // S^T = K Q^T per 16-key block; exp2; packed b64 P-writes (R10 path)
    #pragma unroll
    for (int ntk=0; ntk<4; ntk++){
      short8 kf[4];
      #pragma unroll
      for (int kc=0;kc<4;kc++)
        kf[kc] = *(const short8*)&Ks[ntk*16 + n16][kc*32 + quad*8];
      #pragma unroll
      for (int mtq=0;mtq<4;mtq++){
        f32x4 sa = {0.f,0.f,0.f,0.f};
        #pragma unroll
        for (int kc=0;kc<4;kc++)
          sa = __builtin_amdgcn_mfma_f32_16x16x32_bf16(kf[kc], qa[mtq][kc], sa, 0, 0, 0);
        u16 pb[4];
        #pragma unroll
        for (int r=0;r<4;r++){
          float pe = __builtin_amdgcn_exp2f(sa[r]);
          lp[mtq] += pe;
          pb[r] = f2bf(pe);
        }
        uint2 pk;
        pk.x = ((unsigned)pb[1] << 16) | pb[0];
        pk.y = ((unsigned)pb[3] << 16) | pb[2];
        *(uint2*)(Pw + (mtq*16 + n16)*72 + (((ntk*4 + quad) ^ wmask) << 2)) = pk;
      }
    }
    __builtin_amdgcn_s_waitcnt(0xC07F);
    #pragma unroll
    for (int kb=0; kb<2; kb++){
      short8 pf[4];
      #pragma unroll
      for (int mtq=0;mtq<4;mtq++)
        pf[mtq] = *(const short8*)(Pw + (mtq*16 + n16)*72 + (((kb*8 + quad*2) ^ wmask) << 2));
      __builtin_amdgcn_s_setprio(1);
      #pragma unroll
      for (int dt=0; dt<8; dt++){
        short8 vfd = *(const short8*)&Vs[dt*16 + n16][kb*32 + quad*8];
        #pragma unroll
        for (int mtq=0;mtq<4;mtq++)
          o[mtq][dt] = __builtin_amdgcn_mfma_f32_16x16x32_bf16(pf[mtq], vfd, o[mtq][dt], 0, 0, 0);
      }
      __builtin_amdgcn_s_setprio(0);
    }
#endif
  }

  // l: sum across the 4 quads (lane bits 4,5)
  float l[4];
  #pragma unroll
  for (int mt=0;mt<4;mt++){
    float v = lp[mt];
    v += __shfl_xor(v, 16, 64);
    v += __shfl_xor(v, 32, 64);
    l[mt] = v;
  }

  // Epilogue: UNNORMALIZED bf16 partials, lane-packed [row][n16*8+dt]
  // (ch = dt*16+n16); one 16B store per (mt,r), 256B/quad contiguous.
  #pragma unroll
  for (int mt=0;mt<4;mt++){
    #pragma unroll
    for (int r=0;r<4;r++){
      __align__(16) u16 tmp[8];
      #pragma unroll
      for (int dt=0;dt<8;dt++) tmp[dt] = f2bf(o[mt][dt][r]);
      *(uint4*)(Os + (size_t)(q0 + mt*16 + quad*4 + r)*128 + n16*8) = *(uint4*)tmp;
    }
    if (lane < 16)
      ls[q0 + mt*16 + lane] = l[mt];
  }
}

// ---------------------------------------------------------------------------
// Kernel 3b: merge partials -> OmT in CONV layout [q][j], normalized bf16.
// 256 blocks x 32 attn rows so all CUs share the 32 MB reduction.
// attn row = b*1024 + j*8 + hwhi; stored col' encodes ch = (col'&7)*16 +
// (col'>>3); block covers 4 j values x all 1024 hw of one b -> 8B stores.
// ---------------------------------------------------------------------------
__global__ __launch_bounds__(256) void merge_o_kernel(
    const u16* __restrict__ Opart, const float* __restrict__ lpart, int S,
    u16* __restrict__ OmT)
{
  __shared__ u16 Tm[32][136];
  __shared__ float lrow[32];
  const int t = threadIdx.x;
  const int row0 = blockIdx.x * 32;
  const int b  = row0 >> 10;
  const int j0 = (row0 >> 3) & 127;

  if (t < 32){
    float v = 0.f;
    for (int sp=0; sp<S; sp++) v += lpart[sp*8192 + row0 + t];
    lrow[t] = 1.0f / v;
  }

  const int rl = t >> 3;            // 0..31
  const int cb = (t & 7) * 16;      // 0..112
  float acc[16];
  #pragma unroll
  for (int j=0;j<16;j++) acc[j] = 0.f;
  for (int sp=0; sp<S; sp++){
    const u16* p = Opart + (size_t)sp*1048576 + (size_t)(row0 + rl)*128 + cb;
    #pragma unroll
    for (int q=0;q<2;q++){
      ushort4 v = *(const ushort4*)(p + q*8);
      ushort4 w = *(const ushort4*)(p + q*8 + 4);
      acc[q*8+0] += bf2f(v.x); acc[q*8+1] += bf2f(v.y);
      acc[q*8+2] += bf2f(v.z); acc[q*8+3] += bf2f(v.w);
      acc[q*8+4] += bf2f(w.x); acc[q*8+5] += bf2f(w.y);
      acc[q*8+6] += bf2f(w.z); acc[q*8+7] += bf2f(w.w);
    }
  }
  __syncthreads();
  const float inv = lrow[rl];
  #pragma unroll
  for (int j=0;j<16;j++){
    int cp = cb + j;
    int ch = (cp & 7)*16 + (cp >> 3);
    Tm[rl][ch] = f2bf(acc[j] * inv);     // Tm[local attn row][ch]
  }
  __syncthreads();
  // conv-layout output: local row rl = jl*8 + hwhi  (jl = j - j0, 0..3)
  {
    const int hwhi = t >> 5;             // 0..7
    const int chb  = (t & 31) * 4;       // 4 ch per thread
    #pragma unroll
    for (int c=0;c<4;c++){
      int ch = chb + c;
      __align__(8) u16 tmp[4];
      #pragma unroll
      for (int jl=0;jl<4;jl++) tmp[jl] = Tm[jl*8 + hwhi][ch];
      *(uint2*)(OmT + (size_t)(b*1024 + hwhi*128 + ch)*128 + j0) = *(uint2*)tmp;
    }
  }
}

// ---------------------------------------------------------------------------
// Kernel 4: final conv as MFMA + bias + residual (fp32 out).
// D[co][q] = sum_j Ww[co][j] * OmT[q][j];  out = D + Wb + x.
// grid (4 co-tiles, 64 qg); block = 64co x 128q, K=128 single stage.
// ---------------------------------------------------------------------------
__global__ __launch_bounds__(256, 2) void final_mfma_kernel(
    const float* __restrict__ Ww, const float* __restrict__ Wb,
    const u16* __restrict__ OmT, const float* __restrict__ x,
    float* __restrict__ outp)
{
  __shared__ __align__(16) u16 Ws[64][136];
  __shared__ __align__(16) u16 Os[128][136];
  const int co0 = blockIdx.x * 64, qg = blockIdx.y;
  const int b = qg >> 3, hw0 = (qg & 7) * 128;
  const int q0 = qg * 128;                      // == b*1024 + hw0
  const int t = threadIdx.x;
  const int wave = t >> 6, lane = t & 63;
  const int quad = lane >> 4, n16 = lane & 15;

  {
    int row = t >> 2, cbf = (t & 3) * 32;
    const float* sw = Ww + (size_t)(co0 + row)*128 + cbf;
    #pragma unroll
    for (int i=0;i<8;i++){
      float4 v = *(const float4*)(sw + i*4);
      u16* d = &Ws[row][cbf + i*4];
      d[0]=f2bf(v.x); d[1]=f2bf(v.y); d[2]=f2bf(v.z); d[3]=f2bf(v.w);
    }
  }
  {
    int row = t >> 1, cb = (t & 1) * 64;
    const u16* so = OmT + (size_t)(q0 + row)*128 + cb;
    #pragma unroll
    for (int i=0;i<8;i++)
      *(uint4*)&Os[row][cb + i*8] = *(const uint4*)(so + i*8);
  }
  __syncthreads();

  f32x4 acc[4][2];
  #pragma unroll
  for (int mt=0;mt<4;mt++)
    #pragma unroll
    for (int nt=0;nt<2;nt++){ f32x4 z = {0.f,0.f,0.f,0.f}; acc[mt][nt] = z; }

  #pragma unroll
  for (int kc=0; kc<4; kc++){
    short8 xf[2];
    #pragma unroll
    for (int nt=0;nt<2;nt++)
      xf[nt] = *(const short8*)&Os[wave*32 + nt*16 + n16][kc*32 + quad*8];
    #pragma unroll
    for (int mt=0;mt<4;mt++){
      short8 wf = *(const short8*)&Ws[mt*16 + n16][kc*32 + quad*8];
      #pragma unroll
      for (int nt=0;nt<2;nt++)
        acc[mt][nt] = __builtin_amdgcn_mfma_f32_16x16x32_bf16(wf, xf[nt], acc[mt][nt], 0, 0, 0);
    }
  }

  #pragma unroll
  for (int mt=0;mt<4;mt++){
    float4 bv = *(const float4*)&Wb[co0 + mt*16 + quad*4];
    float bb[4] = {bv.x, bv.y, bv.z, bv.w};
    #pragma unroll
    for (int nt=0;nt<2;nt++)
      #pragma unroll
      for (int r=0;r<4;r++){
        size_t idx = (size_t)b*262144 + (size_t)(co0 + mt*16 + quad*4 + r)*1024
                   + hw0 + wave*32 + nt*16 + n16;
        outp[idx] = acc[mt][nt][r] + bb[r] + x[idx];
      }
  }
}

// ---------------------------------------------------------------------------
extern "C" void kernel_launch(void* const* d_in, const int* in_sizes, int n_in,
                              void* d_out, int out_size, void* d_ws, size_t ws_size,
                              hipStream_t stream)
{
  (void)in_sizes; (void)n_in; (void)out_size; (void)ws_size;
  const float* x  = (const float*)d_in[0];
  const float* tw = (const float*)d_in[1];
  const float* tb = (const float*)d_in[2];
  const float* pw = (const float*)d_in[3];
  const float* pb = (const float*)d_in[4];
  const float* gw = (const float*)d_in[5];
  const float* gb = (const float*)d_in[6];
  const float* Ww = (const float*)d_in[7];
  const float* Wb = (const float*)d_in[8];
  float* outp = (float*)d_out;

  char* ws = (char*)d_ws;
  const size_t MB = 1u << 20;
  u16*   Tbf   = (u16*)(ws);            // 2 MB  theta bf16 (log2e-scaled), conv-flat
  u16*   PHIbf = (u16*)(ws + 2*MB);     // 2 MB  phi, conv-flat
  u16*   Gbf   = (u16*)(ws + 4*MB);     // 2 MB  g, conv-flat
  u16*   Kbf   = (u16*)(ws + 6*MB);     // 2 MB  K = phi^T  [8192][128]
  u16*   VTbf  = (u16*)(ws + 8*MB);     // 2 MB  VT = g^T   [128][8192]
  // Lifetime overlays (ws >= 43 MB proven by earlier S=16 runs):
  u16*   Opart = (u16*)(ws + 10*MB);    // 16 x 2 MB bf16 partials (attn+)
  u16*   XT    = (u16*)(ws + 10*MB);    // 4 MB x^T bf16 (dead before attn)
  float* lpart = (float*)(ws + 2*MB);   // 512 KB (PHI dead after transpose)
  u16*   OmT   = (u16*)(ws + 4*MB);     // 2 MB merged O (Gbf dead after transpose)

  xcast_kernel<<<dim3(16, 4, 8), 256, 0, stream>>>(x, XT);
  proj_mfma_kernel<<<dim3(3, 64), 256, 0, stream>>>(XT, tw, pw, gw, tb, pb, gb,
                                                    Tbf, PHIbf, Gbf);
  transpose_bf_kernel<<<dim3(128, 2), 256, 0, stream>>>(PHIbf, Kbf, 128, 8192);
  transpose_bf_kernel<<<dim3(2, 128), 256, 0, stream>>>(Gbf, VTbf, 8192, 128);
  attn_kernel<<<dim3(512), 256, 0, stream>>>(Tbf, Kbf, VTbf, Opart, lpart);
  merge_o_kernel<<<dim3(256), 256, 0, stream>>>(Opart, lpart, 16, OmT);
  final_mfma_kernel<<<dim3(4, 64), 256, 0, stream>>>(Ww, Wb, OmT, x, outp);
}

// Round 13
// 162.172 us; speedup vs baseline: 1.3635x; 1.3635x over previous
//
#include <hip/hip_runtime.h>

typedef unsigned short u16;
typedef __attribute__((ext_vector_type(8))) short short8;   // 8 x bf16 (4 VGPRs)
typedef __attribute__((ext_vector_type(4))) float f32x4;    // MFMA accumulator

__device__ __forceinline__ u16 f2bf(float f){
  union { float f; unsigned u; } v; v.f = f;
  unsigned u = v.u;
  u += 0x7fffu + ((u >> 16) & 1u);   // RNE
  return (u16)(u >> 16);
}
__device__ __forceinline__ float bf2f(u16 h){
  union { unsigned u; float f; } v; v.u = ((unsigned)h) << 16;
  return v.f;
}

// ---------------------------------------------------------------------------
// Kernel 0b: x [8][256][1024] fp32 -> XT [8][1024][256] bf16 (cast+transpose).
// grid (16 hw-tiles, 4 c-tiles, 8 b).
// ---------------------------------------------------------------------------
__global__ __launch_bounds__(256) void xcast_kernel(
    const float* __restrict__ x, u16* __restrict__ XT)
{
  __shared__ float tile[64][69];
  const int b = blockIdx.z, c0 = blockIdx.y*64, hw0 = blockIdx.x*64;
  const int t = threadIdx.x;
  {
    int r = t >> 2, cs = (t & 3) * 16;    // r = c-local row
    const float* s = x + (size_t)(b*256 + c0 + r)*1024 + hw0 + cs;
    #pragma unroll
    for (int i=0;i<4;i++)
      *(float4*)&tile[r][cs + i*4] = *(const float4*)(s + i*4);
  }
  __syncthreads();
  {
    int hr = t >> 2, cc = (t & 3) * 16;   // hr = hw-local row
    __align__(16) u16 tmp[16];
    #pragma unroll
    for (int i=0;i<16;i++) tmp[i] = f2bf(tile[cc + i][hr]);
    u16* d = XT + (size_t)(b*1024 + hw0 + hr)*256 + c0 + cc;
    *(uint4*)d     = *(uint4*)&tmp[0];
    *(uint4*)(d+8) = *(uint4*)&tmp[8];
  }
}

// ---------------------------------------------------------------------------
// Kernel 1: MFMA projections with FUSED weight cast (fp32 W staged with
// in-flight f2bf).  D[co][q] = sum_c W[co][c] * XT[q][c] (+bias), bf16
// conv-flat out.  proj 0 (theta) pre-scaled by log2(e) -> attn uses raw
// v_exp_f32.  grid (3 proj, 64 qg); block = 128co x 128q, 4 waves.
// ---------------------------------------------------------------------------
__global__ __launch_bounds__(256, 2) void proj_mfma_kernel(
    const u16* __restrict__ XT,
    const float* __restrict__ tw, const float* __restrict__ pw,
    const float* __restrict__ gw,
    const float* __restrict__ tb, const float* __restrict__ pb,
    const float* __restrict__ gb,
    u16* __restrict__ T, u16* __restrict__ PHI, u16* __restrict__ G)
{
  __shared__ __align__(16) u16 Ws[128][136];
  __shared__ __align__(16) u16 Xs[128][136];
  const int proj = blockIdx.x, qg = blockIdx.y;
  const int b = qg >> 3, hw0 = (qg & 7) * 128;
  const int q0 = qg * 128;                        // == b*1024 + hw0
  const float* Wf   = (proj==0) ? tw : (proj==1) ? pw : gw;
  const float* bias = (proj==0) ? tb : (proj==1) ? pb : gb;
  u16* out          = (proj==0) ? T  : (proj==1) ? PHI : G;
  const float scale = (proj==0) ? 1.4426950408889634f : 1.0f;
  const int t = threadIdx.x;
  const int wave = t >> 6, lane = t & 63;
  const int quad = lane >> 4, n16 = lane & 15;

  f32x4 acc[8][2];
  #pragma unroll
  for (int mt=0;mt<8;mt++)
    #pragma unroll
    for (int nt=0;nt<2;nt++){ f32x4 z = {0.f,0.f,0.f,0.f}; acc[mt][nt] = z; }

  for (int c0 = 0; c0 < 256; c0 += 128){
    __syncthreads();
    {
      int row = t >> 1, cb = (t & 1) * 64;
      const float* s1 = Wf + (size_t)row*256 + c0 + cb;
      #pragma unroll
      for (int i=0;i<16;i++){
        float4 v = *(const float4*)(s1 + i*4);
        u16* d = &Ws[row][cb + i*4];
        d[0]=f2bf(v.x); d[1]=f2bf(v.y); d[2]=f2bf(v.z); d[3]=f2bf(v.w);
      }
      const u16* s2 = XT + (size_t)(q0 + row)*256 + c0 + cb;
      #pragma unroll
      for (int i=0;i<8;i++)
        *(uint4*)&Xs[row][cb + i*8] = *(const uint4*)(s2 + i*8);
    }
    __syncthreads();
    #pragma unroll
    for (int kc=0; kc<4; kc++){
      short8 xf[2];
      #pragma unroll
      for (int nt=0;nt<2;nt++)
        xf[nt] = *(const short8*)&Xs[wave*32 + nt*16 + n16][kc*32 + quad*8];
      #pragma unroll
      for (int mt=0;mt<8;mt++){
        short8 wf = *(const short8*)&Ws[mt*16 + n16][kc*32 + quad*8];
        #pragma unroll
        for (int nt=0;nt<2;nt++)
          acc[mt][nt] = __builtin_amdgcn_mfma_f32_16x16x32_bf16(wf, xf[nt], acc[mt][nt], 0, 0, 0);
      }
    }
  }
  #pragma unroll
  for (int mt=0;mt<8;mt++){
    float4 bv = *(const float4*)&bias[mt*16 + quad*4];
    float bb[4] = {bv.x, bv.y, bv.z, bv.w};
    #pragma unroll
    for (int nt=0;nt<2;nt++)
      #pragma unroll
      for (int r=0;r<4;r++)
        out[(size_t)b*131072 + (size_t)(mt*16 + quad*4 + r)*1024
            + hw0 + wave*32 + nt*16 + n16] = f2bf((acc[mt][nt][r] + bb[r]) * scale);
  }
}

// ---------------------------------------------------------------------------
// Kernel 2: bf16 2D transpose, dst[c][r] = src[r][c].  64x64 tiles.
// ---------------------------------------------------------------------------
__global__ __launch_bounds__(256) void transpose_bf_kernel(
    const u16* __restrict__ src, u16* __restrict__ dst, int R, int C)
{
  __shared__ u16 tile[64][72];
  const int t = threadIdx.x;
  const int c0 = blockIdx.x*64, r0 = blockIdx.y*64;
  {
    int rr = t >> 2, cs = (t & 3) * 16;
    const u16* s = src + (size_t)(r0+rr)*C + c0 + cs;
    uint4 a0 = *(const uint4*)s;
    uint4 a1 = *(const uint4*)(s+8);
    *(uint4*)&tile[rr][cs]   = a0;
    *(uint4*)&tile[rr][cs+8] = a1;
  }
  __syncthreads();
  {
    int cc = t >> 2, rs = (t & 3) * 16;
    __align__(16) u16 tmp[16];
    #pragma unroll
    for (int i=0;i<16;i++) tmp[i] = tile[rs+i][cc];
    u16* d = dst + (size_t)(c0+cc)*R + r0 + rs;
    *(uint4*)d     = *(uint4*)&tmp[0];
    *(uint4*)(d+8) = *(uint4*)&tmp[8];
  }
}

// ---------------------------------------------------------------------------
// Kernel 3: flash attention (no-max softmax), LDS-staged K+V, 64-key tiles,
// key-split S=16, block = 4 waves x 64q.  VERIFIED BEST (R5/R10): global->
// VGPR->ds_write staging, padded unswizzled Ks/Vs, LDS Pall P-path,
// 128 VGPR + 128 acc = exactly the 2-blocks/CU budget.  Six pipelining
// restructures falsified on HW (gload_lds x2: 5-10x HBM traffic; register
// prefetch x2 + producer-consumer + PV16 fusion: scratch spill at the
// 256-reg boundary).  Tq pre-scaled by log2e -> raw v_exp_f32; setprio(1)
// around the PV MFMA cluster.
// ---------------------------------------------------------------------------
__global__ __launch_bounds__(256, 2) void attn_kernel(
    const u16* __restrict__ Tq, const u16* __restrict__ Kk,
    const u16* __restrict__ Vt, u16* __restrict__ Opart,
    float* __restrict__ lpart)
{
  __shared__ __align__(16) u16 Ks[64][136];    // 17408 B
  __shared__ __align__(16) u16 Vs[128][72];    // 18432 B
  __shared__ __align__(16) u16 Pall[4][4608];  // 4 x [64 q][72]

  const int t = threadIdx.x;
  const int wave = t >> 6, lane = t & 63;
  const int quad = lane >> 4, n16 = lane & 15;
  const int s  = blockIdx.x & 15;
  const int qg = blockIdx.x >> 4;
  const int q0 = qg*256 + wave*64;
  u16* Pw = Pall[wave];
  u16*   Os = Opart + (size_t)s * 1048576;
  float* ls = lpart + (size_t)s * 8192;

  short8 qa[4][4];
  #pragma unroll
  for (int mt=0;mt<4;mt++)
    #pragma unroll
    for (int kc=0;kc<4;kc++)
      qa[mt][kc] = *(const short8*)(Tq + (size_t)(q0 + mt*16 + n16)*128 + kc*32 + quad*8);

  f32x4 o[4][8];
  float lp[4];
  #pragma unroll
  for (int mt=0;mt<4;mt++){
    #pragma unroll
    for (int dt=0;dt<8;dt++){ f32x4 z = {0.f,0.f,0.f,0.f}; o[mt][dt] = z; }
    lp[mt] = 0.f;
  }

  const int krow = t >> 2, kcs = (t & 3) * 32;
  const int vrow = t >> 1, vcs = (t & 1) * 32;
  const int wmask = n16 & 14;

  for (int kt = s*8; kt < s*8 + 8; kt++){
    const int key0 = kt * 64;
    __syncthreads();
    #pragma unroll
    for (int i=0;i<4;i++)
      *(uint4*)&Ks[krow][kcs + i*8] =
        *(const uint4*)(Kk + (size_t)(key0 + krow)*128 + kcs + i*8);
    #pragma unroll
    for (int i=0;i<4;i++)
      *(uint4*)&Vs[vrow][vcs + i*8] =
        *(const uint4*)(Vt + (size_t)vrow*8192 + key0 + vcs + i*8);
    __syncthreads();

    // S^T = K Q^T per 16-key block; exp2; packed b64 P-writes
    #pragma unroll
    for (int ntk=0; ntk<4; ntk++){
      short8 kf[4];
      #pragma unroll
      for (int kc=0;kc<4;kc++)
        kf[kc] = *(const short8*)&Ks[ntk*16 + n16][kc*32 + quad*8];
      #pragma unroll
      for (int mtq=0;mtq<4;mtq++){
        f32x4 sa = {0.f,0.f,0.f,0.f};
        #pragma unroll
        for (int kc=0;kc<4;kc++)
          sa = __builtin_amdgcn_mfma_f32_16x16x32_bf16(kf[kc], qa[mtq][kc], sa, 0, 0, 0);
        u16 pb[4];
        #pragma unroll
        for (int r=0;r<4;r++){
          float pe = __builtin_amdgcn_exp2f(sa[r]);
          lp[mtq] += pe;
          pb[r] = f2bf(pe);
        }
        uint2 pk;
        pk.x = ((unsigned)pb[1] << 16) | pb[0];
        pk.y = ((unsigned)pb[3] << 16) | pb[2];
        *(uint2*)(Pw + (mtq*16 + n16)*72 + (((ntk*4 + quad) ^ wmask) << 2)) = pk;
      }
    }

    // drain DS: cross-lane P writes must land before cross-lane P reads
    __builtin_amdgcn_s_waitcnt(0xC07F);

    // O~ += P V, per 32-key half
    #pragma unroll
    for (int kb=0; kb<2; kb++){
      short8 pf[4];
      #pragma unroll
      for (int mtq=0;mtq<4;mtq++)
        pf[mtq] = *(const short8*)(Pw + (mtq*16 + n16)*72 + (((kb*8 + quad*2) ^ wmask) << 2));
      __builtin_amdgcn_s_setprio(1);
      #pragma unroll
      for (int dt=0; dt<8; dt++){
        short8 vfd = *(const short8*)&Vs[dt*16 + n16][kb*32 + quad*8];
        #pragma unroll
        for (int mtq=0;mtq<4;mtq++)
          o[mtq][dt] = __builtin_amdgcn_mfma_f32_16x16x32_bf16(pf[mtq], vfd, o[mtq][dt], 0, 0, 0);
      }
      __builtin_amdgcn_s_setprio(0);
    }
  }

  // l: sum across the 4 quads (lane bits 4,5)
  float l[4];
  #pragma unroll
  for (int mt=0;mt<4;mt++){
    float v = lp[mt];
    v += __shfl_xor(v, 16, 64);
    v += __shfl_xor(v, 32, 64);
    l[mt] = v;
  }

  // Epilogue: UNNORMALIZED bf16 partials, lane-packed [row][n16*8+dt]
  // (ch = dt*16+n16); one 16B store per (mt,r), 256B/quad contiguous.
  #pragma unroll
  for (int mt=0;mt<4;mt++){
    #pragma unroll
    for (int r=0;r<4;r++){
      __align__(16) u16 tmp[8];
      #pragma unroll
      for (int dt=0;dt<8;dt++) tmp[dt] = f2bf(o[mt][dt][r]);
      *(uint4*)(Os + (size_t)(q0 + mt*16 + quad*4 + r)*128 + n16*8) = *(uint4*)tmp;
    }
    if (lane < 16)
      ls[q0 + mt*16 + lane] = l[mt];
  }
}

// ---------------------------------------------------------------------------
// Kernel 3b: merge partials -> OmT in CONV layout [q][j], normalized bf16.
// 256 blocks x 32 attn rows so all CUs share the 32 MB reduction.
// attn row = b*1024 + j*8 + hwhi; stored col' encodes ch = (col'&7)*16 +
// (col'>>3); block covers 4 j values x all 1024 hw of one b -> 8B stores.
// ---------------------------------------------------------------------------
__global__ __launch_bounds__(256) void merge_o_kernel(
    const u16* __restrict__ Opart, const float* __restrict__ lpart, int S,
    u16* __restrict__ OmT)
{
  __shared__ u16 Tm[32][136];
  __shared__ float lrow[32];
  const int t = threadIdx.x;
  const int row0 = blockIdx.x * 32;
  const int b  = row0 >> 10;
  const int j0 = (row0 >> 3) & 127;

  if (t < 32){
    float v = 0.f;
    for (int sp=0; sp<S; sp++) v += lpart[sp*8192 + row0 + t];
    lrow[t] = 1.0f / v;
  }

  const int rl = t >> 3;            // 0..31
  const int cb = (t & 7) * 16;      // 0..112
  float acc[16];
  #pragma unroll
  for (int j=0;j<16;j++) acc[j] = 0.f;
  for (int sp=0; sp<S; sp++){
    const u16* p = Opart + (size_t)sp*1048576 + (size_t)(row0 + rl)*128 + cb;
    #pragma unroll
    for (int q=0;q<2;q++){
      ushort4 v = *(const ushort4*)(p + q*8);
      ushort4 w = *(const ushort4*)(p + q*8 + 4);
      acc[q*8+0] += bf2f(v.x); acc[q*8+1] += bf2f(v.y);
      acc[q*8+2] += bf2f(v.z); acc[q*8+3] += bf2f(v.w);
      acc[q*8+4] += bf2f(w.x); acc[q*8+5] += bf2f(w.y);
      acc[q*8+6] += bf2f(w.z); acc[q*8+7] += bf2f(w.w);
    }
  }
  __syncthreads();
  const float inv = lrow[rl];
  #pragma unroll
  for (int j=0;j<16;j++){
    int cp = cb + j;
    int ch = (cp & 7)*16 + (cp >> 3);
    Tm[rl][ch] = f2bf(acc[j] * inv);     // Tm[local attn row][ch]
  }
  __syncthreads();
  // conv-layout output: local row rl = jl*8 + hwhi  (jl = j - j0, 0..3)
  {
    const int hwhi = t >> 5;             // 0..7
    const int chb  = (t & 31) * 4;       // 4 ch per thread
    #pragma unroll
    for (int c=0;c<4;c++){
      int ch = chb + c;
      __align__(8) u16 tmp[4];
      #pragma unroll
      for (int jl=0;jl<4;jl++) tmp[jl] = Tm[jl*8 + hwhi][ch];
      *(uint2*)(OmT + (size_t)(b*1024 + hwhi*128 + ch)*128 + j0) = *(uint2*)tmp;
    }
  }
}

// ---------------------------------------------------------------------------
// Kernel 4: final conv as MFMA + bias + residual (fp32 out).
// D[co][q] = sum_j Ww[co][j] * OmT[q][j];  out = D + Wb + x.
// grid (4 co-tiles, 64 qg); block = 64co x 128q, K=128 single stage.
// ---------------------------------------------------------------------------
__global__ __launch_bounds__(256, 2) void final_mfma_kernel(
    const float* __restrict__ Ww, const float* __restrict__ Wb,
    const u16* __restrict__ OmT, const float* __restrict__ x,
    float* __restrict__ outp)
{
  __shared__ __align__(16) u16 Ws[64][136];
  __shared__ __align__(16) u16 Os[128][136];
  const int co0 = blockIdx.x * 64, qg = blockIdx.y;
  const int b = qg >> 3, hw0 = (qg & 7) * 128;
  const int q0 = qg * 128;                      // == b*1024 + hw0
  const int t = threadIdx.x;
  const int wave = t >> 6, lane = t & 63;
  const int quad = lane >> 4, n16 = lane & 15;

  {
    int row = t >> 2, cbf = (t & 3) * 32;
    const float* sw = Ww + (size_t)(co0 + row)*128 + cbf;
    #pragma unroll
    for (int i=0;i<8;i++){
      float4 v = *(const float4*)(sw + i*4);
      u16* d = &Ws[row][cbf + i*4];
      d[0]=f2bf(v.x); d[1]=f2bf(v.y); d[2]=f2bf(v.z); d[3]=f2bf(v.w);
    }
  }
  {
    int row = t >> 1, cb = (t & 1) * 64;
    const u16* so = OmT + (size_t)(q0 + row)*128 + cb;
    #pragma unroll
    for (int i=0;i<8;i++)
      *(uint4*)&Os[row][cb + i*8] = *(const uint4*)(so + i*8);
  }
  __syncthreads();

  f32x4 acc[4][2];
  #pragma unroll
  for (int mt=0;mt<4;mt++)
    #pragma unroll
    for (int nt=0;nt<2;nt++){ f32x4 z = {0.f,0.f,0.f,0.f}; acc[mt][nt] = z; }

  #pragma unroll
  for (int kc=0; kc<4; kc++){
    short8 xf[2];
    #pragma unroll
    for (int nt=0;nt<2;nt++)
      xf[nt] = *(const short8*)&Os[wave*32 + nt*16 + n16][kc*32 + quad*8];
    #pragma unroll
    for (int mt=0;mt<4;mt++){
      short8 wf = *(const short8*)&Ws[mt*16 + n16][kc*32 + quad*8];
      #pragma unroll
      for (int nt=0;nt<2;nt++)
        acc[mt][nt] = __builtin_amdgcn_mfma_f32_16x16x32_bf16(wf, xf[nt], acc[mt][nt], 0, 0, 0);
    }
  }

  #pragma unroll
  for (int mt=0;mt<4;mt++){
    float4 bv = *(const float4*)&Wb[co0 + mt*16 + quad*4];
    float bb[4] = {bv.x, bv.y, bv.z, bv.w};
    #pragma unroll
    for (int nt=0;nt<2;nt++)
      #pragma unroll
      for (int r=0;r<4;r++){
        size_t idx = (size_t)b*262144 + (size_t)(co0 + mt*16 + quad*4 + r)*1024
                   + hw0 + wave*32 + nt*16 + n16;
        outp[idx] = acc[mt][nt][r] + bb[r] + x[idx];
      }
  }
}

// ---------------------------------------------------------------------------
extern "C" void kernel_launch(void* const* d_in, const int* in_sizes, int n_in,
                              void* d_out, int out_size, void* d_ws, size_t ws_size,
                              hipStream_t stream)
{
  (void)in_sizes; (void)n_in; (void)out_size; (void)ws_size;
  const float* x  = (const float*)d_in[0];
  const float* tw = (const float*)d_in[1];
  const float* tb = (const float*)d_in[2];
  const float* pw = (const float*)d_in[3];
  const float* pb = (const float*)d_in[4];
  const float* gw = (const float*)d_in[5];
  const float* gb = (const float*)d_in[6];
  const float* Ww = (const float*)d_in[7];
  const float* Wb = (const float*)d_in[8];
  float* outp = (float*)d_out;

  char* ws = (char*)d_ws;
  const size_t MB = 1u << 20;
  u16*   Tbf   = (u16*)(ws);            // 2 MB  theta bf16 (log2e-scaled), conv-flat
  u16*   PHIbf = (u16*)(ws + 2*MB);     // 2 MB  phi, conv-flat
  u16*   Gbf   = (u16*)(ws + 4*MB);     // 2 MB  g, conv-flat
  u16*   Kbf   = (u16*)(ws + 6*MB);     // 2 MB  K = phi^T  [8192][128]
  u16*   VTbf  = (u16*)(ws + 8*MB);     // 2 MB  VT = g^T   [128][8192]
  // Lifetime overlays (ws >= 43 MB proven by earlier S=16 runs):
  u16*   Opart = (u16*)(ws + 10*MB);    // 16 x 2 MB bf16 partials (attn+)
  u16*   XT    = (u16*)(ws + 10*MB);    // 4 MB x^T bf16 (dead before attn)
  float* lpart = (float*)(ws + 2*MB);   // 512 KB (PHI dead after transpose)
  u16*   OmT   = (u16*)(ws + 4*MB);     // 2 MB merged O (Gbf dead after transpose)

  xcast_kernel<<<dim3(16, 4, 8), 256, 0, stream>>>(x, XT);
  proj_mfma_kernel<<<dim3(3, 64), 256, 0, stream>>>(XT, tw, pw, gw, tb, pb, gb,
                                                    Tbf, PHIbf, Gbf);
  transpose_bf_kernel<<<dim3(128, 2), 256, 0, stream>>>(PHIbf, Kbf, 128, 8192);
  transpose_bf_kernel<<<dim3(2, 128), 256, 0, stream>>>(Gbf, VTbf, 8192, 128);
  attn_kernel<<<dim3(512), 256, 0, stream>>>(Tbf, Kbf, VTbf, Opart, lpart);
  merge_o_kernel<<<dim3(256), 256, 0, stream>>>(Opart, lpart, 16, OmT);
  final_mfma_kernel<<<dim3(4, 64), 256, 0, stream>>>(Ww, Wb, OmT, x, outp);
}

// Round 14
// 161.989 us; speedup vs baseline: 1.3651x; 1.0011x over previous
//
#include <hip/hip_runtime.h>

typedef unsigned short u16;
typedef __attribute__((ext_vector_type(8))) short short8;   // 8 x bf16 (4 VGPRs)
typedef __attribute__((ext_vector_type(4))) float f32x4;    // MFMA accumulator

__device__ __forceinline__ u16 f2bf(float f){
  union { float f; unsigned u; } v; v.f = f;
  unsigned u = v.u;
  u += 0x7fffu + ((u >> 16) & 1u);   // RNE
  return (u16)(u >> 16);
}
__device__ __forceinline__ float bf2f(u16 h){
  union { unsigned u; float f; } v; v.u = ((unsigned)h) << 16;
  return v.f;
}

// ---------------------------------------------------------------------------
// Kernel 0b: x [8][256][1024] fp32 -> XT [8][1024][256] bf16 (cast+transpose).
// grid (16 hw-tiles, 4 c-tiles, 8 b).
// ---------------------------------------------------------------------------
__global__ __launch_bounds__(256) void xcast_kernel(
    const float* __restrict__ x, u16* __restrict__ XT)
{
  __shared__ float tile[64][69];
  const int b = blockIdx.z, c0 = blockIdx.y*64, hw0 = blockIdx.x*64;
  const int t = threadIdx.x;
  {
    int r = t >> 2, cs = (t & 3) * 16;    // r = c-local row
    const float* s = x + (size_t)(b*256 + c0 + r)*1024 + hw0 + cs;
    #pragma unroll
    for (int i=0;i<4;i++)
      *(float4*)&tile[r][cs + i*4] = *(const float4*)(s + i*4);
  }
  __syncthreads();
  {
    int hr = t >> 2, cc = (t & 3) * 16;   // hr = hw-local row
    __align__(16) u16 tmp[16];
    #pragma unroll
    for (int i=0;i<16;i++) tmp[i] = f2bf(tile[cc + i][hr]);
    u16* d = XT + (size_t)(b*1024 + hw0 + hr)*256 + c0 + cc;
    *(uint4*)d     = *(uint4*)&tmp[0];
    *(uint4*)(d+8) = *(uint4*)&tmp[8];
  }
}

// ---------------------------------------------------------------------------
// Kernel 1: MFMA projections with FUSED weight cast (fp32 W staged with
// in-flight f2bf).  D[co][q] = sum_c W[co][c] * XT[q][c] (+bias), bf16
// conv-flat out.  proj 0 (theta) pre-scaled by log2(e) -> attn uses raw
// v_exp_f32.  grid (3 proj, 64 qg); block = 128co x 128q, 4 waves.
// ---------------------------------------------------------------------------
__global__ __launch_bounds__(256, 2) void proj_mfma_kernel(
    const u16* __restrict__ XT,
    const float* __restrict__ tw, const float* __restrict__ pw,
    const float* __restrict__ gw,
    const float* __restrict__ tb, const float* __restrict__ pb,
    const float* __restrict__ gb,
    u16* __restrict__ T, u16* __restrict__ PHI, u16* __restrict__ G)
{
  __shared__ __align__(16) u16 Ws[128][136];
  __shared__ __align__(16) u16 Xs[128][136];
  const int proj = blockIdx.x, qg = blockIdx.y;
  const int b = qg >> 3, hw0 = (qg & 7) * 128;
  const int q0 = qg * 128;                        // == b*1024 + hw0
  const float* Wf   = (proj==0) ? tw : (proj==1) ? pw : gw;
  const float* bias = (proj==0) ? tb : (proj==1) ? pb : gb;
  u16* out          = (proj==0) ? T  : (proj==1) ? PHI : G;
  const float scale = (proj==0) ? 1.4426950408889634f : 1.0f;
  const int t = threadIdx.x;
  const int wave = t >> 6, lane = t & 63;
  const int quad = lane >> 4, n16 = lane & 15;

  f32x4 acc[8][2];
  #pragma unroll
  for (int mt=0;mt<8;mt++)
    #pragma unroll
    for (int nt=0;nt<2;nt++){ f32x4 z = {0.f,0.f,0.f,0.f}; acc[mt][nt] = z; }

  for (int c0 = 0; c0 < 256; c0 += 128){
    __syncthreads();
    {
      int row = t >> 1, cb = (t & 1) * 64;
      const float* s1 = Wf + (size_t)row*256 + c0 + cb;
      #pragma unroll
      for (int i=0;i<16;i++){
        float4 v = *(const float4*)(s1 + i*4);
        u16* d = &Ws[row][cb + i*4];
        d[0]=f2bf(v.x); d[1]=f2bf(v.y); d[2]=f2bf(v.z); d[3]=f2bf(v.w);
      }
      const u16* s2 = XT + (size_t)(q0 + row)*256 + c0 + cb;
      #pragma unroll
      for (int i=0;i<8;i++)
        *(uint4*)&Xs[row][cb + i*8] = *(const uint4*)(s2 + i*8);
    }
    __syncthreads();
    #pragma unroll
    for (int kc=0; kc<4; kc++){
      short8 xf[2];
      #pragma unroll
      for (int nt=0;nt<2;nt++)
        xf[nt] = *(const short8*)&Xs[wave*32 + nt*16 + n16][kc*32 + quad*8];
      #pragma unroll
      for (int mt=0;mt<8;mt++){
        short8 wf = *(const short8*)&Ws[mt*16 + n16][kc*32 + quad*8];
        #pragma unroll
        for (int nt=0;nt<2;nt++)
          acc[mt][nt] = __builtin_amdgcn_mfma_f32_16x16x32_bf16(wf, xf[nt], acc[mt][nt], 0, 0, 0);
      }
    }
  }
  #pragma unroll
  for (int mt=0;mt<8;mt++){
    float4 bv = *(const float4*)&bias[mt*16 + quad*4];
    float bb[4] = {bv.x, bv.y, bv.z, bv.w};
    #pragma unroll
    for (int nt=0;nt<2;nt++)
      #pragma unroll
      for (int r=0;r<4;r++)
        out[(size_t)b*131072 + (size_t)(mt*16 + quad*4 + r)*1024
            + hw0 + wave*32 + nt*16 + n16] = f2bf((acc[mt][nt][r] + bb[r]) * scale);
  }
}

// ---------------------------------------------------------------------------
// Kernel 2: DUAL bf16 2D transpose -- both independent transposes in ONE
// launch, selected by blockIdx.z (body identical to the verified
// transpose_bf_kernel).  grid (128, 2, 2):
//   z=0: PHIbf[128][8192] -> Kbf[8192][128];  c0=bx*64 (<8192), r0=by*64 (<128)
//   z=1: Gbf[8192][128]  -> VTbf[128][8192];  c0=by*64 (<128), r0=bx*64 (<8192)
// Mapping checked against both original calls: all 2x128 tiles covered.
// ---------------------------------------------------------------------------
__global__ __launch_bounds__(256) void transpose_dual_kernel(
    const u16* __restrict__ PHIbf, u16* __restrict__ Kbf,
    const u16* __restrict__ Gbf,  u16* __restrict__ VTbf)
{
  __shared__ u16 tile[64][72];
  const int t = threadIdx.x;
  const int z = blockIdx.z;
  const u16* src = (z == 0) ? PHIbf : Gbf;
  u16*       dst = (z == 0) ? Kbf   : VTbf;
  const int R = (z == 0) ? 128  : 8192;
  const int C = (z == 0) ? 8192 : 128;
  const int c0 = ((z == 0) ? blockIdx.x : blockIdx.y) * 64;
  const int r0 = ((z == 0) ? blockIdx.y : blockIdx.x) * 64;
  {
    int rr = t >> 2, cs = (t & 3) * 16;
    const u16* s = src + (size_t)(r0+rr)*C + c0 + cs;
    uint4 a0 = *(const uint4*)s;
    uint4 a1 = *(const uint4*)(s+8);
    *(uint4*)&tile[rr][cs]   = a0;
    *(uint4*)&tile[rr][cs+8] = a1;
  }
  __syncthreads();
  {
    int cc = t >> 2, rs = (t & 3) * 16;
    __align__(16) u16 tmp[16];
    #pragma unroll
    for (int i=0;i<16;i++) tmp[i] = tile[rs+i][cc];
    u16* d = dst + (size_t)(c0+cc)*R + r0 + rs;
    *(uint4*)d     = *(uint4*)&tmp[0];
    *(uint4*)(d+8) = *(uint4*)&tmp[8];
  }
}

// ---------------------------------------------------------------------------
// Kernel 3: flash attention (no-max softmax), LDS-staged K+V, 64-key tiles,
// key-split S=16, block = 4 waves x 64q.  VERIFIED BEST (R5/R10/R13):
// global->VGPR->ds_write staging, padded unswizzled Ks/Vs, LDS Pall P-path,
// 128 VGPR + 128 acc = exactly the 2-blocks/CU budget.  Six pipelining
// restructures falsified on HW (gload_lds x2: 5-10x HBM traffic; register
// prefetch x2 + producer-consumer + PV16 fusion: scratch spill at the
// 256-reg boundary).  Tq pre-scaled by log2e -> raw v_exp_f32; setprio(1)
// around the PV MFMA cluster.
// ---------------------------------------------------------------------------
__global__ __launch_bounds__(256, 2) void attn_kernel(
    const u16* __restrict__ Tq, const u16* __restrict__ Kk,
    const u16* __restrict__ Vt, u16* __restrict__ Opart,
    float* __restrict__ lpart)
{
  __shared__ __align__(16) u16 Ks[64][136];    // 17408 B
  __shared__ __align__(16) u16 Vs[128][72];    // 18432 B
  __shared__ __align__(16) u16 Pall[4][4608];  // 4 x [64 q][72]

  const int t = threadIdx.x;
  const int wave = t >> 6, lane = t & 63;
  const int quad = lane >> 4, n16 = lane & 15;
  const int s  = blockIdx.x & 15;
  const int qg = blockIdx.x >> 4;
  const int q0 = qg*256 + wave*64;
  u16* Pw = Pall[wave];
  u16*   Os = Opart + (size_t)s * 1048576;
  float* ls = lpart + (size_t)s * 8192;

  short8 qa[4][4];
  #pragma unroll
  for (int mt=0;mt<4;mt++)
    #pragma unroll
    for (int kc=0;kc<4;kc++)
      qa[mt][kc] = *(const short8*)(Tq + (size_t)(q0 + mt*16 + n16)*128 + kc*32 + quad*8);

  f32x4 o[4][8];
  float lp[4];
  #pragma unroll
  for (int mt=0;mt<4;mt++){
    #pragma unroll
    for (int dt=0;dt<8;dt++){ f32x4 z = {0.f,0.f,0.f,0.f}; o[mt][dt] = z; }
    lp[mt] = 0.f;
  }

  const int krow = t >> 2, kcs = (t & 3) * 32;
  const int vrow = t >> 1, vcs = (t & 1) * 32;
  const int wmask = n16 & 14;

  for (int kt = s*8; kt < s*8 + 8; kt++){
    const int key0 = kt * 64;
    __syncthreads();
    #pragma unroll
    for (int i=0;i<4;i++)
      *(uint4*)&Ks[krow][kcs + i*8] =
        *(const uint4*)(Kk + (size_t)(key0 + krow)*128 + kcs + i*8);
    #pragma unroll
    for (int i=0;i<4;i++)
      *(uint4*)&Vs[vrow][vcs + i*8] =
        *(const uint4*)(Vt + (size_t)vrow*8192 + key0 + vcs + i*8);
    __syncthreads();

    // S^T = K Q^T per 16-key block; exp2; packed b64 P-writes
    #pragma unroll
    for (int ntk=0; ntk<4; ntk++){
      short8 kf[4];
      #pragma unroll
      for (int kc=0;kc<4;kc++)
        kf[kc] = *(const short8*)&Ks[ntk*16 + n16][kc*32 + quad*8];
      #pragma unroll
      for (int mtq=0;mtq<4;mtq++){
        f32x4 sa = {0.f,0.f,0.f,0.f};
        #pragma unroll
        for (int kc=0;kc<4;kc++)
          sa = __builtin_amdgcn_mfma_f32_16x16x32_bf16(kf[kc], qa[mtq][kc], sa, 0, 0, 0);
        u16 pb[4];
        #pragma unroll
        for (int r=0;r<4;r++){
          float pe = __builtin_amdgcn_exp2f(sa[r]);
          lp[mtq] += pe;
          pb[r] = f2bf(pe);
        }
        uint2 pk;
        pk.x = ((unsigned)pb[1] << 16) | pb[0];
        pk.y = ((unsigned)pb[3] << 16) | pb[2];
        *(uint2*)(Pw + (mtq*16 + n16)*72 + (((ntk*4 + quad) ^ wmask) << 2)) = pk;
      }
    }

    // drain DS: cross-lane P writes must land before cross-lane P reads
    __builtin_amdgcn_s_waitcnt(0xC07F);

    // O~ += P V, per 32-key half
    #pragma unroll
    for (int kb=0; kb<2; kb++){
      short8 pf[4];
      #pragma unroll
      for (int mtq=0;mtq<4;mtq++)
        pf[mtq] = *(const short8*)(Pw + (mtq*16 + n16)*72 + (((kb*8 + quad*2) ^ wmask) << 2));
      __builtin_amdgcn_s_setprio(1);
      #pragma unroll
      for (int dt=0; dt<8; dt++){
        short8 vfd = *(const short8*)&Vs[dt*16 + n16][kb*32 + quad*8];
        #pragma unroll
        for (int mtq=0;mtq<4;mtq++)
          o[mtq][dt] = __builtin_amdgcn_mfma_f32_16x16x32_bf16(pf[mtq], vfd, o[mtq][dt], 0, 0, 0);
      }
      __builtin_amdgcn_s_setprio(0);
    }
  }

  // l: sum across the 4 quads (lane bits 4,5)
  float l[4];
  #pragma unroll
  for (int mt=0;mt<4;mt++){
    float v = lp[mt];
    v += __shfl_xor(v, 16, 64);
    v += __shfl_xor(v, 32, 64);
    l[mt] = v;
  }

  // Epilogue: UNNORMALIZED bf16 partials, lane-packed [row][n16*8+dt]
  // (ch = dt*16+n16); one 16B store per (mt,r), 256B/quad contiguous.
  #pragma unroll
  for (int mt=0;mt<4;mt++){
    #pragma unroll
    for (int r=0;r<4;r++){
      __align__(16) u16 tmp[8];
      #pragma unroll
      for (int dt=0;dt<8;dt++) tmp[dt] = f2bf(o[mt][dt][r]);
      *(uint4*)(Os + (size_t)(q0 + mt*16 + quad*4 + r)*128 + n16*8) = *(uint4*)tmp;
    }
    if (lane < 16)
      ls[q0 + mt*16 + lane] = l[mt];
  }
}

// ---------------------------------------------------------------------------
// Kernel 3b: merge partials -> OmT in CONV layout [q][j], normalized bf16.
// 256 blocks x 32 attn rows so all CUs share the 32 MB reduction.
// attn row = b*1024 + j*8 + hwhi; stored col' encodes ch = (col'&7)*16 +
// (col'>>3); block covers 4 j values x all 1024 hw of one b -> 8B stores.
// ---------------------------------------------------------------------------
__global__ __launch_bounds__(256) void merge_o_kernel(
    const u16* __restrict__ Opart, const float* __restrict__ lpart, int S,
    u16* __restrict__ OmT)
{
  __shared__ u16 Tm[32][136];
  __shared__ float lrow[32];
  const int t = threadIdx.x;
  const int row0 = blockIdx.x * 32;
  const int b  = row0 >> 10;
  const int j0 = (row0 >> 3) & 127;

  if (t < 32){
    float v = 0.f;
    for (int sp=0; sp<S; sp++) v += lpart[sp*8192 + row0 + t];
    lrow[t] = 1.0f / v;
  }

  const int rl = t >> 3;            // 0..31
  const int cb = (t & 7) * 16;      // 0..112
  float acc[16];
  #pragma unroll
  for (int j=0;j<16;j++) acc[j] = 0.f;
  for (int sp=0; sp<S; sp++){
    const u16* p = Opart + (size_t)sp*1048576 + (size_t)(row0 + rl)*128 + cb;
    #pragma unroll
    for (int q=0;q<2;q++){
      ushort4 v = *(const ushort4*)(p + q*8);
      ushort4 w = *(const ushort4*)(p + q*8 + 4);
      acc[q*8+0] += bf2f(v.x); acc[q*8+1] += bf2f(v.y);
      acc[q*8+2] += bf2f(v.z); acc[q*8+3] += bf2f(v.w);
      acc[q*8+4] += bf2f(w.x); acc[q*8+5] += bf2f(w.y);
      acc[q*8+6] += bf2f(w.z); acc[q*8+7] += bf2f(w.w);
    }
  }
  __syncthreads();
  const float inv = lrow[rl];
  #pragma unroll
  for (int j=0;j<16;j++){
    int cp = cb + j;
    int ch = (cp & 7)*16 + (cp >> 3);
    Tm[rl][ch] = f2bf(acc[j] * inv);     // Tm[local attn row][ch]
  }
  __syncthreads();
  // conv-layout output: local row rl = jl*8 + hwhi  (jl = j - j0, 0..3)
  {
    const int hwhi = t >> 5;             // 0..7
    const int chb  = (t & 31) * 4;       // 4 ch per thread
    #pragma unroll
    for (int c=0;c<4;c++){
      int ch = chb + c;
      __align__(8) u16 tmp[4];
      #pragma unroll
      for (int jl=0;jl<4;jl++) tmp[jl] = Tm[jl*8 + hwhi][ch];
      *(uint2*)(OmT + (size_t)(b*1024 + hwhi*128 + ch)*128 + j0) = *(uint2*)tmp;
    }
  }
}

// ---------------------------------------------------------------------------
// Kernel 4: final conv as MFMA + bias + residual (fp32 out).
// D[co][q] = sum_j Ww[co][j] * OmT[q][j];  out = D + Wb + x.
// grid (4 co-tiles, 64 qg); block = 64co x 128q, K=128 single stage.
// ---------------------------------------------------------------------------
__global__ __launch_bounds__(256, 2) void final_mfma_kernel(
    const float* __restrict__ Ww, const float* __restrict__ Wb,
    const u16* __restrict__ OmT, const float* __restrict__ x,
    float* __restrict__ outp)
{
  __shared__ __align__(16) u16 Ws[64][136];
  __shared__ __align__(16) u16 Os[128][136];
  const int co0 = blockIdx.x * 64, qg = blockIdx.y;
  const int b = qg >> 3, hw0 = (qg & 7) * 128;
  const int q0 = qg * 128;                      // == b*1024 + hw0
  const int t = threadIdx.x;
  const int wave = t >> 6, lane = t & 63;
  const int quad = lane >> 4, n16 = lane & 15;

  {
    int row = t >> 2, cbf = (t & 3) * 32;
    const float* sw = Ww + (size_t)(co0 + row)*128 + cbf;
    #pragma unroll
    for (int i=0;i<8;i++){
      float4 v = *(const float4*)(sw + i*4);
      u16* d = &Ws[row][cbf + i*4];
      d[0]=f2bf(v.x); d[1]=f2bf(v.y); d[2]=f2bf(v.z); d[3]=f2bf(v.w);
    }
  }
  {
    int row = t >> 1, cb = (t & 1) * 64;
    const u16* so = OmT + (size_t)(q0 + row)*128 + cb;
    #pragma unroll
    for (int i=0;i<8;i++)
      *(uint4*)&Os[row][cb + i*8] = *(const uint4*)(so + i*8);
  }
  __syncthreads();

  f32x4 acc[4][2];
  #pragma unroll
  for (int mt=0;mt<4;mt++)
    #pragma unroll
    for (int nt=0;nt<2;nt++){ f32x4 z = {0.f,0.f,0.f,0.f}; acc[mt][nt] = z; }

  #pragma unroll
  for (int kc=0; kc<4; kc++){
    short8 xf[2];
    #pragma unroll
    for (int nt=0;nt<2;nt++)
      xf[nt] = *(const short8*)&Os[wave*32 + nt*16 + n16][kc*32 + quad*8];
    #pragma unroll
    for (int mt=0;mt<4;mt++){
      short8 wf = *(const short8*)&Ws[mt*16 + n16][kc*32 + quad*8];
      #pragma unroll
      for (int nt=0;nt<2;nt++)
        acc[mt][nt] = __builtin_amdgcn_mfma_f32_16x16x32_bf16(wf, xf[nt], acc[mt][nt], 0, 0, 0);
    }
  }

  #pragma unroll
  for (int mt=0;mt<4;mt++){
    float4 bv = *(const float4*)&Wb[co0 + mt*16 + quad*4];
    float bb[4] = {bv.x, bv.y, bv.z, bv.w};
    #pragma unroll
    for (int nt=0;nt<2;nt++)
      #pragma unroll
      for (int r=0;r<4;r++){
        size_t idx = (size_t)b*262144 + (size_t)(co0 + mt*16 + quad*4 + r)*1024
                   + hw0 + wave*32 + nt*16 + n16;
        outp[idx] = acc[mt][nt][r] + bb[r] + x[idx];
      }
  }
}

// ---------------------------------------------------------------------------
extern "C" void kernel_launch(void* const* d_in, const int* in_sizes, int n_in,
                              void* d_out, int out_size, void* d_ws, size_t ws_size,
                              hipStream_t stream)
{
  (void)in_sizes; (void)n_in; (void)out_size; (void)ws_size;
  const float* x  = (const float*)d_in[0];
  const float* tw = (const float*)d_in[1];
  const float* tb = (const float*)d_in[2];
  const float* pw = (const float*)d_in[3];
  const float* pb = (const float*)d_in[4];
  const float* gw = (const float*)d_in[5];
  const float* gb = (const float*)d_in[6];
  const float* Ww = (const float*)d_in[7];
  const float* Wb = (const float*)d_in[8];
  float* outp = (float*)d_out;

  char* ws = (char*)d_ws;
  const size_t MB = 1u << 20;
  u16*   Tbf   = (u16*)(ws);            // 2 MB  theta bf16 (log2e-scaled), conv-flat
  u16*   PHIbf = (u16*)(ws + 2*MB);     // 2 MB  phi, conv-flat
  u16*   Gbf   = (u16*)(ws + 4*MB);     // 2 MB  g, conv-flat
  u16*   Kbf   = (u16*)(ws + 6*MB);     // 2 MB  K = phi^T  [8192][128]
  u16*   VTbf  = (u16*)(ws + 8*MB);     // 2 MB  VT = g^T   [128][8192]
  // Lifetime overlays (ws >= 43 MB proven by earlier S=16 runs):
  u16*   Opart = (u16*)(ws + 10*MB);    // 16 x 2 MB bf16 partials (attn+)
  u16*   XT    = (u16*)(ws + 10*MB);    // 4 MB x^T bf16 (dead before attn)
  float* lpart = (float*)(ws + 2*MB);   // 512 KB (PHI dead after transpose)
  u16*   OmT   = (u16*)(ws + 4*MB);     // 2 MB merged O (Gbf dead after transpose)

  xcast_kernel<<<dim3(16, 4, 8), 256, 0, stream>>>(x, XT);
  proj_mfma_kernel<<<dim3(3, 64), 256, 0, stream>>>(XT, tw, pw, gw, tb, pb, gb,
                                                    Tbf, PHIbf, Gbf);
  transpose_dual_kernel<<<dim3(128, 2, 2), 256, 0, stream>>>(PHIbf, Kbf, Gbf, VTbf);
  attn_kernel<<<dim3(512), 256, 0, stream>>>(Tbf, Kbf, VTbf, Opart, lpart);
  merge_o_kernel<<<dim3(256), 256, 0, stream>>>(Opart, lpart, 16, OmT);
  final_mfma_kernel<<<dim3(4, 64), 256, 0, stream>>>(Ww, Wb, OmT, x, outp);
}